// Round 2
// baseline (333.059 us; speedup 1.0000x reference)
//
#include <hip/hip_runtime.h>
#include <hip/hip_bf16.h>
#include <stdint.h>

// Output per (b, seg, np, chunk, p): 4x4 = mean over frames of [x;1][x;1]^T
// (cov + mu*muT == E[x xT]).  3 unique segment types (chunk len 136/68/45);
// out segs {0},{1,2},{3,4,5} duplicate stypes 0/1/2.
// Single-read strategy: the 9 moment sums per (b,j,frame-range) are
// stype-independent; partition [0,2048) at the union of all chunk
// boundaries -> each "piece" lies in exactly one chunk of every stype.
// Phase 1 reads x once, emits per-piece sums; phase 2 gathers + finalizes.

#define MAXP 64
struct PieceTab { int n; uint32_t p[MAXP]; };   // p = f0 | (len<<16)

// ---------------- Phase 1: per-piece moment sums ----------------
__global__ __launch_bounds__(256) void p1_kernel(const float* __restrict__ x,
                                                 float* __restrict__ ws,
                                                 PieceTab tab) {
    __shared__ float lds[2250];   // [250 threads][9 sums]
    int pc = blockIdx.x;
    int b  = blockIdx.y;
    uint32_t pk = tab.p[pc];
    int f0  = pk & 0xffff;
    int len = pk >> 16;           // <= 50

    int tid = threadIdx.x;
    if (tid < 250) {
        int j = tid % 25, tsub = tid / 25;
        const float* base = x + (size_t)b * 153600 + (size_t)f0 * 75 + j * 3;
        float s0=0.f,s1=0.f,s2=0.f,s3=0.f,s4=0.f,s5=0.f,s6=0.f,s7=0.f,s8=0.f;
        #pragma unroll 5
        for (int t = tsub; t < len; t += 10) {
            const float* p = base + (size_t)t * 75;
            float x0 = p[0], x1 = p[1], x2 = p[2];
            s0 += x0;     s1 += x1;     s2 += x2;
            s3 += x0*x0;  s4 += x0*x1;  s5 += x0*x2;
            s6 += x1*x1;  s7 += x1*x2;  s8 += x2*x2;
        }
        float* l = &lds[tid * 9];
        l[0]=s0; l[1]=s1; l[2]=s2; l[3]=s3; l[4]=s4; l[5]=s5; l[6]=s6; l[7]=s7; l[8]=s8;
    }
    __syncthreads();

    if (tid < 225) {   // cell = j*9+si ; lds[(ts*25+j)*9+si] == lds[ts*225+tid]
        float v = 0.f;
        #pragma unroll
        for (int ts = 0; ts < 10; ++ts) v += lds[ts * 225 + tid];
        ws[((size_t)b * tab.n + pc) * 225 + tid] = v;
    }
}

// ---------------- Phase 2: gather pieces, finalize, write ----------------
__global__ __launch_bounds__(256) void p2_kernel(const float* __restrict__ ws,
                                                 float* __restrict__ out,
                                                 PieceTab tab) {
    __shared__ float red[225];
    __shared__ float outm[400];

    int bid   = blockIdx.x;       // b*45 + stype*15 + chunk
    int chunk = bid % 15;
    int tmp   = bid / 15;
    int stype = tmp % 3;
    int b     = tmp / 3;

    const int nbs[3] = {136, 68, 45};
    int ns = nbs[stype];
    int nfr = (chunk == 14) ? (2048 - 14 * ns) : ns;
    float inv_n = 1.0f / (float)nfr;

    int tid = threadIdx.x;
    if (tid < 225) {
        float v = 0.f;
        const float* wb = ws + (size_t)b * tab.n * 225 + tid;
        for (int p = 0; p < tab.n; ++p) {
            int f0 = tab.p[p] & 0xffff;      // wave-uniform
            int c = f0 / ns; if (c > 14) c = 14;
            if (c == chunk) v += wb[(size_t)p * 225];
        }
        red[tid] = v;
    }
    __syncthreads();

    if (tid < 25) {
        const float* r = &red[tid * 9];
        float mu0 = r[0]*inv_n, mu1 = r[1]*inv_n, mu2 = r[2]*inv_n;
        float m00 = r[3]*inv_n, m01 = r[4]*inv_n, m02 = r[5]*inv_n;
        float m11 = r[6]*inv_n, m12 = r[7]*inv_n, m22 = r[8]*inv_n;
        float* o = &outm[tid * 16];
        o[0]=m00; o[1]=m01; o[2]=m02; o[3]=mu0;
        o[4]=m01; o[5]=m11; o[6]=m12; o[7]=mu1;
        o[8]=m02; o[9]=m12; o[10]=m22; o[11]=mu2;
        o[12]=mu0; o[13]=mu1; o[14]=mu2; o[15]=1.0f;
    }
    __syncthreads();

    int so0  = (stype == 0) ? 0 : (stype == 1) ? 1 : 3;
    int ndup = (stype == 0) ? 1 : (stype == 1) ? 2 : 3;
    int total = 400 * ndup;
    size_t obase = (size_t)b * 36000 + (size_t)chunk * 80;
    for (int idx = tid; idx < total; idx += 256) {
        int dup = idx / 400;
        int r   = idx % 400;
        int np  = r / 80;
        int rem = r % 80;
        out[obase + (size_t)(so0 + dup) * 6000 + (size_t)np * 1200 + rem] = outm[r];
    }
}

// ---------------- Fallback (round-1 kernel, known-correct) ----------------
__global__ __launch_bounds__(256) void gauss_fallback(const float* __restrict__ x,
                                                      float* __restrict__ out) {
    __shared__ float lds[2250];
    __shared__ float red[225];
    __shared__ float outm[400];

    int bid   = blockIdx.x;
    int chunk = bid % 15;
    int tmp   = bid / 15;
    int stype = tmp % 3;
    int b     = tmp / 3;

    const int nbs[3] = {136, 68, 45};
    int ns = nbs[stype];
    int f0 = chunk * ns;
    int f1 = (chunk == 14) ? 2048 : (f0 + ns);
    float inv_n = 1.0f / (float)(f1 - f0);

    int tid = threadIdx.x;
    if (tid < 250) {
        int j    = tid % 25;
        int tsub = tid / 25;
        const float* base = x + (size_t)b * 153600 + j * 3;
        float s0=0.f,s1=0.f,s2=0.f,s3=0.f,s4=0.f,s5=0.f,s6=0.f,s7=0.f,s8=0.f;
        for (int t = f0 + tsub; t < f1; t += 10) {
            const float* p = base + (size_t)t * 75;
            float x0 = p[0], x1 = p[1], x2 = p[2];
            s0 += x0;     s1 += x1;     s2 += x2;
            s3 += x0*x0;  s4 += x0*x1;  s5 += x0*x2;
            s6 += x1*x1;  s7 += x1*x2;  s8 += x2*x2;
        }
        float* l = &lds[tid * 9];
        l[0]=s0; l[1]=s1; l[2]=s2; l[3]=s3; l[4]=s4; l[5]=s5; l[6]=s6; l[7]=s7; l[8]=s8;
    }
    __syncthreads();
    if (tid < 225) {
        float v = 0.f;
        #pragma unroll
        for (int ts = 0; ts < 10; ++ts) v += lds[ts * 225 + tid];
        red[tid] = v;
    }
    __syncthreads();
    if (tid < 25) {
        const float* r = &red[tid * 9];
        float mu0 = r[0]*inv_n, mu1 = r[1]*inv_n, mu2 = r[2]*inv_n;
        float m00 = r[3]*inv_n, m01 = r[4]*inv_n, m02 = r[5]*inv_n;
        float m11 = r[6]*inv_n, m12 = r[7]*inv_n, m22 = r[8]*inv_n;
        float* o = &outm[tid * 16];
        o[0]=m00; o[1]=m01; o[2]=m02; o[3]=mu0;
        o[4]=m01; o[5]=m11; o[6]=m12; o[7]=mu1;
        o[8]=m02; o[9]=m12; o[10]=m22; o[11]=mu2;
        o[12]=mu0; o[13]=mu1; o[14]=mu2; o[15]=1.0f;
    }
    __syncthreads();
    int so0  = (stype == 0) ? 0 : (stype == 1) ? 1 : 3;
    int ndup = (stype == 0) ? 1 : (stype == 1) ? 2 : 3;
    int total = 400 * ndup;
    size_t obase = (size_t)b * 36000 + (size_t)chunk * 80;
    for (int idx = tid; idx < total; idx += 256) {
        int dup = idx / 400;
        int r   = idx % 400;
        int np  = r / 80;
        int rem = r % 80;
        out[obase + (size_t)(so0 + dup) * 6000 + (size_t)np * 1200 + rem] = outm[r];
    }
}

// ---------------- Host ----------------
static int build_pieces(uint32_t* pk) {
    // Boundary union of all three stypes' chunk edges, segments split to <=50.
    unsigned char isb[2049];
    for (int i = 0; i <= 2048; ++i) isb[i] = 0;
    isb[2048] = 1;
    for (int k = 1; k <= 14; ++k) { isb[45*k] = 1; isb[68*k] = 1; isb[136*k] = 1; }
    int n = 0, prev = 0;
    for (int f = 1; f <= 2048; ++f) {
        if (!isb[f]) continue;
        int len = f - prev;
        int np = (len + 49) / 50;
        int base = len / np, rem = len % np;
        int s = prev;
        for (int i = 0; i < np; ++i) {
            int l = base + (i < rem ? 1 : 0);
            pk[n++] = (uint32_t)(s | (l << 16));
            s += l;
        }
        prev = f;
    }
    return n;   // 56 for T=2048
}

extern "C" void kernel_launch(void* const* d_in, const int* in_sizes, int n_in,
                              void* d_out, int out_size, void* d_ws, size_t ws_size,
                              hipStream_t stream) {
    const float* x = (const float*)d_in[0];
    float* out = (float*)d_out;

    PieceTab tab;
    tab.n = build_pieces(tab.p);
    size_t need = (size_t)256 * tab.n * 225 * sizeof(float);   // ~12.9 MB

    if (ws_size >= need && tab.n <= MAXP) {
        float* ws = (float*)d_ws;
        dim3 g1(tab.n, 256);
        p1_kernel<<<g1, 256, 0, stream>>>(x, ws, tab);
        p2_kernel<<<256 * 45, 256, 0, stream>>>(ws, out, tab);
    } else {
        gauss_fallback<<<256 * 45, 256, 0, stream>>>(x, out);
    }
}

// Round 3
// 245.285 us; speedup vs baseline: 1.3578x; 1.3578x over previous
//
#include <hip/hip_runtime.h>
#include <hip/hip_bf16.h>
#include <stdint.h>

// out[b, seg, np, chunk, p, 4, 4] = mean over the chunk's frames of
// [x;1][x;1]^T  (cov + mu muT == E[y yT]).  3 unique chunk lengths
// (136/68/45); out segs {0},{1,2},{3,4,5} duplicate stypes 0/1/2.
//
// p1: partition [0,2048) at the union of all chunk boundaries (pieces <=50
//     frames, never crossing any chunk edge). One block per (piece,b):
//     float4-stage piece into LDS, accumulate 25j x 9 moment sums, write ws.
// p2: per (b,np): gather piece sums (contiguous piece range per chunk,
//     host-precomputed), finalize 4x4s, stream coalesced writes.

#define NPIECE_MAX 64
struct Tab {
    int n;                      // #pieces (56 for T=2048)
    uint32_t p[NPIECE_MAX];     // f0 | (len<<16)
    uint32_t cr[45];            // per (stype*15+chunk): pstart | (pend<<16)
};

// ---------------- Phase 1 ----------------
__global__ __launch_bounds__(256) void p1_kernel(const float* __restrict__ x,
                                                 float* __restrict__ ws, Tab tab) {
    __shared__ float sx[3756];   // 15 KB: staged piece, then reused for partials
    int pc = blockIdx.x, b = blockIdx.y;
    uint32_t pk = tab.p[pc];
    int f0 = pk & 0xffff, L = (int)(pk >> 16);   // L <= 50
    int w0 = f0 * 75;
    int base_f = w0 & ~3;        // align to 16 B
    int shift = w0 - base_f;     // 0..3
    int nv4 = (shift + L * 75 + 3) >> 2;
    const float4* src = (const float4*)(x + (size_t)b * 153600 + base_f);
    int tid = threadIdx.x;
    for (int i = tid; i < nv4; i += 256)
        ((float4*)sx)[i] = src[i];
    __syncthreads();

    float s[9] = {0,0,0,0,0,0,0,0,0};
    if (tid < 250) {
        int j = tid % 25, ts = tid / 25;
        for (int t = ts; t < L; t += 10) {
            const float* p = &sx[shift + t * 75 + j * 3];
            float a = p[0], bb = p[1], c = p[2];
            s[0]+=a;    s[1]+=bb;   s[2]+=c;
            s[3]+=a*a;  s[4]+=a*bb; s[5]+=a*c;
            s[6]+=bb*bb; s[7]+=bb*c; s[8]+=c*c;
        }
    }
    __syncthreads();            // everyone done reading sx
    if (tid < 250) {
        float* l = &sx[tid * 9];  // stride 9: coprime w/ 32 banks -> 2-way max
        #pragma unroll
        for (int k = 0; k < 9; ++k) l[k] = s[k];
    }
    __syncthreads();
    if (tid < 225) {            // cell j*9+si ; partial at sx[ts*225 + cell]
        float v = 0.f;
        #pragma unroll
        for (int ts = 0; ts < 10; ++ts) v += sx[ts * 225 + tid];
        ws[((size_t)b * tab.n + pc) * 225 + tid] = v;
    }
}

// ---------------- Phase 2: per (b, np) ----------------
__global__ __launch_bounds__(256) void p2_kernel(const float* __restrict__ ws,
                                                 float* __restrict__ out, Tab tab) {
    __shared__ float sws[2520];  // [piece][j_local*9+si], 56*45
    __shared__ float red[2025];  // [stype*15+chunk][j_local*9+si]
    __shared__ float invn[45];
    int b = blockIdx.x, np = blockIdx.y;
    int tid = threadIdx.x;
    int n = tab.n;
    int tot = n * 45;
    const float* wb = ws + (size_t)b * n * 225 + np * 45;
    for (int i = tid; i < tot; i += 256) {
        int piece = i / 45, idx = i - piece * 45;
        sws[i] = wb[(size_t)piece * 225 + idx];   // 180 B contiguous runs
    }
    if (tid < 45) {
        int st = tid / 15, ch = tid - st * 15;
        const int nst[3] = {136, 68, 45};
        int ns = nst[st];
        int nfr = (ch == 14) ? (2048 - 14 * ns) : ns;
        invn[tid] = 1.0f / (float)nfr;
    }
    __syncthreads();

    for (int i = tid; i < 2025; i += 256) {
        int sc = i / 45, idx = i - sc * 45;
        uint32_t r = tab.cr[sc];
        int p0 = (int)(r & 0xffff), p1 = (int)(r >> 16);
        float v = 0.f;
        for (int p = p0; p < p1; ++p) v += sws[p * 45 + idx];
        red[i] = v;
    }
    __syncthreads();

    float* ob = out + (size_t)b * 36000 + (size_t)np * 1200;
    for (int o = tid; o < 7200; o += 256) {
        int seg = o / 1200;
        int r1  = o - seg * 1200;        // chunk*80 + p*16 + e
        int ch  = r1 / 80;
        int r3  = r1 - ch * 80;
        int p   = r3 >> 4;
        int e   = r3 & 15;
        int st  = (seg == 0) ? 0 : (seg < 3) ? 1 : 2;
        int sc  = st * 15 + ch;
        int r   = e >> 2, c = e & 3;
        float v;
        if (r == 3 && c == 3) {
            v = 1.0f;
        } else {
            int mi;
            if (r == 3) mi = c;
            else if (c == 3) mi = r;
            else {
                int lo = (r < c) ? r : c;
                int hi = r + c - lo;
                mi = 3 + ((lo * (5 - lo)) >> 1) + hi;   // sym 3x3 -> 3..8
            }
            v = red[sc * 45 + p * 9 + mi] * invn[sc];
        }
        ob[(size_t)seg * 6000 + r1] = v;
    }
}

// ---------------- Fallback (round-1 fused, known-correct) ----------------
__global__ __launch_bounds__(256) void gauss_fallback(const float* __restrict__ x,
                                                      float* __restrict__ out) {
    __shared__ float lds[2250];
    __shared__ float red[225];
    __shared__ float outm[400];
    int bid = blockIdx.x;
    int chunk = bid % 15;
    int tmp = bid / 15;
    int stype = tmp % 3;
    int b = tmp / 3;
    const int nbs[3] = {136, 68, 45};
    int ns = nbs[stype];
    int f0 = chunk * ns;
    int f1 = (chunk == 14) ? 2048 : (f0 + ns);
    float inv_n = 1.0f / (float)(f1 - f0);
    int tid = threadIdx.x;
    if (tid < 250) {
        int j = tid % 25, tsub = tid / 25;
        const float* base = x + (size_t)b * 153600 + j * 3;
        float s0=0.f,s1=0.f,s2=0.f,s3=0.f,s4=0.f,s5=0.f,s6=0.f,s7=0.f,s8=0.f;
        for (int t = f0 + tsub; t < f1; t += 10) {
            const float* p = base + (size_t)t * 75;
            float x0 = p[0], x1 = p[1], x2 = p[2];
            s0+=x0; s1+=x1; s2+=x2;
            s3+=x0*x0; s4+=x0*x1; s5+=x0*x2;
            s6+=x1*x1; s7+=x1*x2; s8+=x2*x2;
        }
        float* l = &lds[tid * 9];
        l[0]=s0; l[1]=s1; l[2]=s2; l[3]=s3; l[4]=s4; l[5]=s5; l[6]=s6; l[7]=s7; l[8]=s8;
    }
    __syncthreads();
    if (tid < 225) {
        float v = 0.f;
        #pragma unroll
        for (int ts = 0; ts < 10; ++ts) v += lds[ts * 225 + tid];
        red[tid] = v;
    }
    __syncthreads();
    if (tid < 25) {
        const float* r = &red[tid * 9];
        float mu0=r[0]*inv_n, mu1=r[1]*inv_n, mu2=r[2]*inv_n;
        float m00=r[3]*inv_n, m01=r[4]*inv_n, m02=r[5]*inv_n;
        float m11=r[6]*inv_n, m12=r[7]*inv_n, m22=r[8]*inv_n;
        float* o = &outm[tid * 16];
        o[0]=m00; o[1]=m01; o[2]=m02; o[3]=mu0;
        o[4]=m01; o[5]=m11; o[6]=m12; o[7]=mu1;
        o[8]=m02; o[9]=m12; o[10]=m22; o[11]=mu2;
        o[12]=mu0; o[13]=mu1; o[14]=mu2; o[15]=1.0f;
    }
    __syncthreads();
    int so0 = (stype == 0) ? 0 : (stype == 1) ? 1 : 3;
    int ndup = (stype == 0) ? 1 : (stype == 1) ? 2 : 3;
    int total = 400 * ndup;
    size_t obase = (size_t)b * 36000 + (size_t)chunk * 80;
    for (int idx = tid; idx < total; idx += 256) {
        int dup = idx / 400;
        int r = idx % 400;
        int np = r / 80;
        int rem = r % 80;
        out[obase + (size_t)(so0 + dup) * 6000 + (size_t)np * 1200 + rem] = outm[r];
    }
}

// ---------------- Host ----------------
static void build_tab(Tab& tab) {
    unsigned char isb[2049];
    for (int i = 0; i <= 2048; ++i) isb[i] = 0;
    isb[2048] = 1;
    for (int k = 1; k <= 14; ++k) { isb[45*k] = 1; isb[68*k] = 1; isb[136*k] = 1; }
    int n = 0, prev = 0;
    int pf0[NPIECE_MAX];
    for (int f = 1; f <= 2048; ++f) {
        if (!isb[f]) continue;
        int len = f - prev;
        int npc = (len + 49) / 50;
        int base = len / npc, rem = len % npc;
        int s = prev;
        for (int i = 0; i < npc && n < NPIECE_MAX; ++i) {
            int l = base + (i < rem ? 1 : 0);
            pf0[n] = s;
            tab.p[n++] = (uint32_t)(s | (l << 16));
            s += l;
        }
        prev = f;
    }
    tab.n = n;   // 56
    const int nst[3] = {136, 68, 45};
    for (int st = 0; st < 3; ++st) {
        int ns = nst[st];
        for (int c = 0; c < 15; ++c) {
            int a = c * ns, bnd = (c == 14) ? 2048 : (c + 1) * ns;
            int p0 = 0; while (p0 < n && pf0[p0] < a) ++p0;
            int p1 = p0; while (p1 < n && pf0[p1] < bnd) ++p1;
            tab.cr[st * 15 + c] = (uint32_t)(p0 | (p1 << 16));
        }
    }
}

extern "C" void kernel_launch(void* const* d_in, const int* in_sizes, int n_in,
                              void* d_out, int out_size, void* d_ws, size_t ws_size,
                              hipStream_t stream) {
    const float* x = (const float*)d_in[0];
    float* out = (float*)d_out;

    Tab tab;
    build_tab(tab);
    size_t need = (size_t)256 * tab.n * 225 * sizeof(float);   // ~12.9 MB

    if (ws_size >= need) {
        float* ws = (float*)d_ws;
        dim3 g1(tab.n, 256);
        p1_kernel<<<g1, 256, 0, stream>>>(x, ws, tab);
        dim3 g2(256, 5);
        p2_kernel<<<g2, 256, 0, stream>>>(ws, out, tab);
    } else {
        gauss_fallback<<<256 * 45, 256, 0, stream>>>(x, out);
    }
}

// Round 4
// 238.151 us; speedup vs baseline: 1.3985x; 1.0300x over previous
//
#include <hip/hip_runtime.h>
#include <hip/hip_bf16.h>
#include <stdint.h>

// out[b, seg, np, chunk, p, 4, 4] = mean over the chunk's frames of
// [x;1][x;1]^T  (cov + mu muT == E[y yT]).  3 unique chunk lengths
// (136/68/45); out segs {0},{1,2},{3,4,5} duplicate stypes 0/1/2.
//
// p1: pieces = partition of [0,2048) at the union of all chunk boundaries
//     (<=50 frames, never crossing a chunk edge). One block per (piece,b):
//     global_load_lds (width 16) stages the piece, block reduces 25j x 9
//     moments, writes ws.
// p2: per (b,np): gather contiguous piece-range sums per chunk
//     (host-precomputed ranges), finalize 4x4s, float4 coalesced stores.

#define NPIECE_MAX 64
struct Tab {
    int n;                      // #pieces (56 for T=2048)
    uint32_t p[NPIECE_MAX];     // f0 | (len<<16)
    uint32_t cr[45];            // per (stype*15+chunk): pstart | (pend<<16)
};

// ---------------- Phase 1 ----------------
__global__ __launch_bounds__(256) void p1_kernel(const float* __restrict__ x,
                                                 float* __restrict__ ws, Tab tab) {
    __shared__ float sx[3760];   // staged piece (<=939 float4), reused for partials
    int pc = blockIdx.x, b = blockIdx.y;
    uint32_t pk = tab.p[pc];
    int f0 = pk & 0xffff, L = (int)(pk >> 16);   // L <= 50
    int w0 = f0 * 75;
    int base_f = w0 & ~3;        // 16 B align
    int shift = w0 - base_f;     // 0..3
    int nv4 = (shift + L * 75 + 3) >> 2;         // never crosses b-row end
    const float4* src = (const float4*)(x + (size_t)b * 153600 + base_f);
    int tid = threadIdx.x;
    int wv = tid >> 6, ln = tid & 63;
    #pragma unroll
    for (int k = 0; k < 4; ++k) {                // 4*256 = 1024 >= 939
        int i = k * 256 + wv * 64 + ln;
        if (i < nv4) {
            __builtin_amdgcn_global_load_lds(
                (const __attribute__((address_space(1))) void*)(src + i),
                (__attribute__((address_space(3))) void*)(&sx[(size_t)(k * 256 + wv * 64) * 4]),
                16, 0, 0);
        }
    }
    __syncthreads();             // drains vmcnt before any LDS read

    float s[9] = {0,0,0,0,0,0,0,0,0};
    if (tid < 250) {
        int j = tid % 25, ts = tid / 25;
        #pragma unroll 5
        for (int t = ts; t < L; t += 10) {
            const float* p = &sx[shift + t * 75 + j * 3];
            float a = p[0], bb = p[1], c = p[2];
            s[0]+=a;     s[1]+=bb;   s[2]+=c;
            s[3]+=a*a;   s[4]+=a*bb; s[5]+=a*c;
            s[6]+=bb*bb; s[7]+=bb*c; s[8]+=c*c;
        }
    }
    __syncthreads();            // everyone done reading sx
    if (tid < 250) {
        float* l = &sx[tid * 9];
        #pragma unroll
        for (int k = 0; k < 9; ++k) l[k] = s[k];
    }
    __syncthreads();
    if (tid < 225) {            // cell j*9+si ; partial at sx[ts*225 + cell]
        float v = 0.f;
        #pragma unroll
        for (int ts = 0; ts < 10; ++ts) v += sx[ts * 225 + tid];
        ws[((size_t)b * tab.n + pc) * 225 + tid] = v;
    }
}

// ---------------- Phase 2: per (b, np) ----------------
// moment-index nibble table, entry (r*4+c): row r of the 4x4 -> red offset
// rows 0..2: {3,4,5,0},{4,6,7,1},{5,7,8,2}; row 3: {0,1,2,(9=dummy)}
#define IDXPK 0x9210287517640543ull

__global__ __launch_bounds__(256) void p2_kernel(const float* __restrict__ ws,
                                                 float* __restrict__ out, Tab tab) {
    __shared__ float sws[2520];  // [piece][j_local*9+si], 56*45
    __shared__ float red[2032];  // [stype*15+chunk][j_local*9+si] (+pad for dummy idx 9)
    __shared__ float invn[45];
    int b = blockIdx.x, np = blockIdx.y;
    int tid = threadIdx.x;
    int n = tab.n;
    int tot = n * 45;
    const float* wb = ws + (size_t)b * n * 225 + np * 45;
    for (int i = tid; i < tot; i += 256) {
        int piece = i / 45, idx = i - piece * 45;
        sws[i] = wb[(size_t)piece * 225 + idx];   // 180 B contiguous runs
    }
    if (tid < 45) {
        int st = tid / 15, ch = tid - st * 15;
        const int nst[3] = {136, 68, 45};
        int ns = nst[st];
        int nfr = (ch == 14) ? (2048 - 14 * ns) : ns;
        invn[tid] = 1.0f / (float)nfr;
    }
    __syncthreads();

    for (int i = tid; i < 2025; i += 256) {
        int sc = i / 45, idx = i - sc * 45;
        uint32_t r = tab.cr[sc];
        int p0 = (int)(r & 0xffff), p1 = (int)(r >> 16);
        float v = 0.f;
        for (int p = p0; p < p1; ++p) v += sws[p * 45 + idx];
        red[i] = v;
    }
    __syncthreads();

    // 1800 float4 stores per block: q -> (seg, chunk, p, row)
    float4* ob4 = (float4*)(out + (size_t)b * 36000 + (size_t)np * 1200);
    for (int q = tid; q < 1800; q += 256) {
        int seg = q / 300;
        int q2  = q - seg * 300;        // ch*20 + p*4 + r
        int ch  = q2 / 20;
        int rem = q2 - ch * 20;
        int p   = rem >> 2;
        int r   = rem & 3;
        int st  = (seg == 0) ? 0 : (seg < 3) ? 1 : 2;
        int sc  = st * 15 + ch;
        float inv = invn[sc];
        const float* rb = &red[sc * 45 + p * 9];
        uint64_t pk = IDXPK >> (16 * r);
        float4 v;
        v.x = rb[(int)(pk       & 15)] * inv;
        v.y = rb[(int)((pk >> 4) & 15)] * inv;
        v.z = rb[(int)((pk >> 8) & 15)] * inv;
        v.w = (r == 3) ? 1.0f : rb[(int)((pk >> 12) & 15)] * inv;
        ob4[(size_t)seg * 1500 + q2] = v;
    }
}

// ---------------- Fallback (round-1 fused, known-correct) ----------------
__global__ __launch_bounds__(256) void gauss_fallback(const float* __restrict__ x,
                                                      float* __restrict__ out) {
    __shared__ float lds[2250];
    __shared__ float red[225];
    __shared__ float outm[400];
    int bid = blockIdx.x;
    int chunk = bid % 15;
    int tmp = bid / 15;
    int stype = tmp % 3;
    int b = tmp / 3;
    const int nbs[3] = {136, 68, 45};
    int ns = nbs[stype];
    int f0 = chunk * ns;
    int f1 = (chunk == 14) ? 2048 : (f0 + ns);
    float inv_n = 1.0f / (float)(f1 - f0);
    int tid = threadIdx.x;
    if (tid < 250) {
        int j = tid % 25, tsub = tid / 25;
        const float* base = x + (size_t)b * 153600 + j * 3;
        float s0=0.f,s1=0.f,s2=0.f,s3=0.f,s4=0.f,s5=0.f,s6=0.f,s7=0.f,s8=0.f;
        for (int t = f0 + tsub; t < f1; t += 10) {
            const float* p = base + (size_t)t * 75;
            float x0 = p[0], x1 = p[1], x2 = p[2];
            s0+=x0; s1+=x1; s2+=x2;
            s3+=x0*x0; s4+=x0*x1; s5+=x0*x2;
            s6+=x1*x1; s7+=x1*x2; s8+=x2*x2;
        }
        float* l = &lds[tid * 9];
        l[0]=s0; l[1]=s1; l[2]=s2; l[3]=s3; l[4]=s4; l[5]=s5; l[6]=s6; l[7]=s7; l[8]=s8;
    }
    __syncthreads();
    if (tid < 225) {
        float v = 0.f;
        #pragma unroll
        for (int ts = 0; ts < 10; ++ts) v += lds[ts * 225 + tid];
        red[tid] = v;
    }
    __syncthreads();
    if (tid < 25) {
        const float* r = &red[tid * 9];
        float mu0=r[0]*inv_n, mu1=r[1]*inv_n, mu2=r[2]*inv_n;
        float m00=r[3]*inv_n, m01=r[4]*inv_n, m02=r[5]*inv_n;
        float m11=r[6]*inv_n, m12=r[7]*inv_n, m22=r[8]*inv_n;
        float* o = &outm[tid * 16];
        o[0]=m00; o[1]=m01; o[2]=m02; o[3]=mu0;
        o[4]=m01; o[5]=m11; o[6]=m12; o[7]=mu1;
        o[8]=m02; o[9]=m12; o[10]=m22; o[11]=mu2;
        o[12]=mu0; o[13]=mu1; o[14]=mu2; o[15]=1.0f;
    }
    __syncthreads();
    int so0 = (stype == 0) ? 0 : (stype == 1) ? 1 : 3;
    int ndup = (stype == 0) ? 1 : (stype == 1) ? 2 : 3;
    int total = 400 * ndup;
    size_t obase = (size_t)b * 36000 + (size_t)chunk * 80;
    for (int idx = tid; idx < total; idx += 256) {
        int dup = idx % 400 == idx ? idx / 400 : idx / 400;  // dup index
        int r = idx % 400;
        int np = r / 80;
        int rem = r % 80;
        out[obase + (size_t)(so0 + idx / 400) * 6000 + (size_t)np * 1200 + rem] = outm[r];
    }
}

// ---------------- Host ----------------
static void build_tab(Tab& tab) {
    unsigned char isb[2049];
    for (int i = 0; i <= 2048; ++i) isb[i] = 0;
    isb[2048] = 1;
    for (int k = 1; k <= 14; ++k) { isb[45*k] = 1; isb[68*k] = 1; isb[136*k] = 1; }
    int n = 0, prev = 0;
    int pf0[NPIECE_MAX];
    for (int f = 1; f <= 2048; ++f) {
        if (!isb[f]) continue;
        int len = f - prev;
        int npc = (len + 49) / 50;
        int base = len / npc, rem = len % npc;
        int s = prev;
        for (int i = 0; i < npc && n < NPIECE_MAX; ++i) {
            int l = base + (i < rem ? 1 : 0);
            pf0[n] = s;
            tab.p[n++] = (uint32_t)(s | (l << 16));
            s += l;
        }
        prev = f;
    }
    tab.n = n;   // 56
    const int nst[3] = {136, 68, 45};
    for (int st = 0; st < 3; ++st) {
        int ns = nst[st];
        for (int c = 0; c < 15; ++c) {
            int a = c * ns, bnd = (c == 14) ? 2048 : (c + 1) * ns;
            int p0 = 0; while (p0 < n && pf0[p0] < a) ++p0;
            int p1 = p0; while (p1 < n && pf0[p1] < bnd) ++p1;
            tab.cr[st * 15 + c] = (uint32_t)(p0 | (p1 << 16));
        }
    }
}

extern "C" void kernel_launch(void* const* d_in, const int* in_sizes, int n_in,
                              void* d_out, int out_size, void* d_ws, size_t ws_size,
                              hipStream_t stream) {
    const float* x = (const float*)d_in[0];
    float* out = (float*)d_out;

    Tab tab;
    build_tab(tab);
    size_t need = (size_t)256 * tab.n * 225 * sizeof(float);   // ~12.9 MB

    if (ws_size >= need) {
        float* ws = (float*)d_ws;
        dim3 g1(tab.n, 256);
        p1_kernel<<<g1, 256, 0, stream>>>(x, ws, tab);
        dim3 g2(256, 5);
        p2_kernel<<<g2, 256, 0, stream>>>(ws, out, tab);
    } else {
        gauss_fallback<<<256 * 45, 256, 0, stream>>>(x, out);
    }
}